// Round 1
// baseline (1324.232 us; speedup 1.0000x reference)
//
#include <hip/hip_runtime.h>

// GPTQ 4-bit dequant GEMM, two-pass: out[M,N] = x[M,K] @ W[K,N]
// W[k,n] = scales[k/128, n] * (nibble(qweight,k,n) - (nibble(qzeros,k/128,n)+1))
// M = 8192, K = 4096, N = 11008, GROUP = 128.
//
// Pass 1: x fp32 -> bf16 (workspace).           ~32 us, memory-bound.
// Pass 2: qweight -> W^T [N,K] bf16 (workspace) ~18 us; dequant runs ONCE
//         instead of once per M-tile (64x) as in the fused kernel.
// Pass 3: m97-structure bf16 GEMM: 128x128 tile, BK=64, global_load_lds
//         width=16 for A and B^T, read-side XOR swizzle (T2, rule #21:
//         linear LDS dest + inverse-swizzled global source + swizzled read),
//         XCD-aware block swizzle (T1).
// Falls back to the previous fused kernel if workspace is too small.

typedef __bf16 bf16;
typedef __attribute__((ext_vector_type(8))) __bf16 bf16x8;
typedef __attribute__((ext_vector_type(4))) __bf16 bf16x4;
typedef __attribute__((ext_vector_type(4))) float floatx4;

constexpr int KDIM = 4096;
constexpr int NDIM = 11008;
constexpr int GROUP = 128;
constexpr int BM = 128, BN = 128, BK = 64;
constexpr int NBX = NDIM / BN;   // 86

// ---------------- pass 1: x fp32 -> bf16 ----------------
__global__ __launch_bounds__(256)
void cvt_x(const float* __restrict__ x, bf16* __restrict__ xb) {
  const int idx = (blockIdx.x * 256 + threadIdx.x) * 8;
  const float4 a = *(const float4*)&x[idx];
  const float4 b = *(const float4*)&x[idx + 4];
  bf16x8 pk = { (bf16)a.x, (bf16)a.y, (bf16)a.z, (bf16)a.w,
                (bf16)b.x, (bf16)b.y, (bf16)b.z, (bf16)b.w };
  *(bf16x8*)&xb[idx] = pk;
}

// ---------------- pass 2: dequant qweight -> W^T [N, K] bf16 ----------------
// One thread per column n, one group (128 k) per blockIdx.y.
// Reads coalesced along n; each lane writes a 256B k-contiguous run (L2
// write-combines the 16B pieces into full lines).
__global__ __launch_bounds__(256)
void dequant_wt(const int* __restrict__ qweight, const int* __restrict__ qzeros,
                const float* __restrict__ scales, bf16* __restrict__ wt) {
  const int n = blockIdx.x * 256 + threadIdx.x;
  const int g = blockIdx.y;
  const float sc = scales[g * NDIM + n];
  const unsigned zw = (unsigned)qzeros[g * (NDIM / 8) + (n >> 3)];
  const float zs = (float)(((zw >> ((n & 7) * 4)) & 0xF) + 1) * sc;
  const int kp0 = (g * GROUP) >> 3;           // 16 packed words per group
  const int obase = n * KDIM + g * GROUP;
#pragma unroll
  for (int i = 0; i < 16; ++i) {
    const unsigned w = (unsigned)qweight[(kp0 + i) * NDIM + n];
    bf16x8 pk;
#pragma unroll
    for (int j = 0; j < 8; ++j)
      pk[j] = (bf16)((float)((w >> (4 * j)) & 0xF) * sc - zs);  // sc*(q-z)
    *(bf16x8*)&wt[obase + i * 8] = pk;
  }
}

// ---------------- pass 3: bf16 GEMM (m97 structure) ----------------
// A [M,K] bf16, BT [N,K] bf16, both k-contiguous. Linear LDS [128][64],
// global_load_lds dwordx4; chunk swizzle c ^= (row&7) applied on the
// per-lane global source and again on the ds_read_b128 fragment reads.
__global__ __launch_bounds__(256)
void gemm_bf16(const bf16* __restrict__ A, const bf16* __restrict__ BT,
               float* __restrict__ out) {
  __shared__ bf16 As[BM * BK];
  __shared__ bf16 Bs[BN * BK];

  const int tid  = threadIdx.x;
  const int lane = tid & 63;
  const int wave = tid >> 6;
  const int quad = lane >> 4;
  const int l16  = lane & 15;
  const int wm   = (wave >> 1) * 64;
  const int wn   = (wave & 1) * 64;

  // T1: XCD-aware block swizzle (bijective when nwg % 8 == 0)
  const int nwg = gridDim.x * gridDim.y;
  const int orig = blockIdx.y * gridDim.x + blockIdx.x;
  int wg = orig;
  if ((nwg & 7) == 0) wg = (orig & 7) * (nwg >> 3) + (orig >> 3);
  const int bx = wg % NBX;
  const int by = wg / NBX;
  const int row0 = by * BM;
  const int col0 = bx * BN;

  // staging geometry: one wave instruction covers 8 rows x 128B (1 KiB).
  // lane i -> LDS row srow=i>>3, chunk i&7 (linear dest). We want LDS(r,c)
  // to hold global chunk c ^ (r&7), so lane fetches chunk (i&7)^(i>>3).
  const int srow   = lane >> 3;
  const int schunk = (lane & 7) ^ srow;
  const int soff   = srow * KDIM + schunk * 8;   // element offset within 8-row group

  floatx4 acc[4][4];
#pragma unroll
  for (int i = 0; i < 4; ++i)
#pragma unroll
    for (int j = 0; j < 4; ++j) acc[i][j] = (floatx4)0.f;

  for (int ks = 0; ks < KDIM / BK; ++ks) {
    const int k0 = ks * BK;
#pragma unroll
    for (int t4 = 0; t4 < 4; ++t4) {
      const int t = wave * 4 + t4;               // 16 groups of 8 rows
      const int ga = (row0 + t * 8) * KDIM + k0 + soff;
      __builtin_amdgcn_global_load_lds(
          (const __attribute__((address_space(1))) void*)(A + ga),
          (__attribute__((address_space(3))) void*)&As[t * 8 * BK], 16, 0, 0);
      const int gb = (col0 + t * 8) * KDIM + k0 + soff;
      __builtin_amdgcn_global_load_lds(
          (const __attribute__((address_space(1))) void*)(BT + gb),
          (__attribute__((address_space(3))) void*)&Bs[t * 8 * BK], 16, 0, 0);
    }
    __syncthreads();   // compiler emits vmcnt(0) drain before s_barrier

#pragma unroll
    for (int kk = 0; kk < 2; ++kk) {
      bf16x8 af[4], bfr[4];
#pragma unroll
      for (int i = 0; i < 4; ++i) {
        const int r = wm + i * 16 + l16;
        af[i] = *(bf16x8*)&As[r * BK + (((kk * 4 + quad) ^ (r & 7)) << 3)];
      }
#pragma unroll
      for (int j = 0; j < 4; ++j) {
        const int r = wn + j * 16 + l16;
        bfr[j] = *(bf16x8*)&Bs[r * BK + (((kk * 4 + quad) ^ (r & 7)) << 3)];
      }
#pragma unroll
      for (int i = 0; i < 4; ++i)
#pragma unroll
        for (int j = 0; j < 4; ++j)
          acc[i][j] = __builtin_amdgcn_mfma_f32_16x16x32_bf16(af[i], bfr[j], acc[i][j], 0, 0, 0);
    }
    __syncthreads();
  }

  // epilogue: C/D layout col=lane&15, row=quad*4+reg (m89-verified)
#pragma unroll
  for (int i = 0; i < 4; ++i) {
#pragma unroll
    for (int j = 0; j < 4; ++j) {
      const int r0 = row0 + wm + i * 16 + quad * 4;
      const int c  = col0 + wn + j * 16 + l16;
#pragma unroll
      for (int r = 0; r < 4; ++r)
        out[(r0 + r) * NDIM + c] = acc[i][j][r];
    }
  }
}

// ---------------- fallback: previous fused kernel (349 TF) ----------------
__global__ __launch_bounds__(256)
void gptq_gemm(const float* __restrict__ x, const int* __restrict__ qweight,
               const int* __restrict__ qzeros, const float* __restrict__ scales,
               float* __restrict__ out) {
  constexpr int FBK = 32;
  constexpr int LDT = 40;
  __shared__ bf16 As[BM * LDT];
  __shared__ bf16 Bs[BN * LDT];

  const int tid  = threadIdx.x;
  const int lane = tid & 63;
  const int wave = tid >> 6;
  const int quad = lane >> 4;
  const int l16  = lane & 15;
  const int wm   = (wave >> 1) * 64;
  const int wn   = (wave & 1) * 64;

  const int row0 = blockIdx.y * BM;
  const int col0 = blockIdx.x * BN;

  const int nb   = tid & 127;
  const int kpl0 = tid >> 7;
  const int gn   = col0 + nb;

  floatx4 acc[4][4];
#pragma unroll
  for (int i = 0; i < 4; ++i)
#pragma unroll
    for (int j = 0; j < 4; ++j) acc[i][j] = (floatx4)0.f;

  const int NGROUPS = KDIM / GROUP;

  for (int g = 0; g < NGROUPS; ++g) {
    const float sc = scales[g * NDIM + gn];
    const unsigned int zw = (unsigned int)qzeros[g * (NDIM / 8) + (gn >> 3)];
    const int z = (int)((zw >> ((gn & 7) * 4)) & 0xF) + 1;
    const float zs = (float)z * sc;

    for (int kk = 0; kk < GROUP / FBK; ++kk) {
      const int k0 = g * GROUP + kk * FBK;
#pragma unroll
      for (int r = 0; r < 4; ++r) {
        const int flat = r * 256 + tid;
        const int m  = flat >> 3;
        const int k4 = (flat & 7) << 2;
        const float4 v = *(const float4*)&x[(row0 + m) * KDIM + k0 + k4];
        bf16x4 pk = { (bf16)v.x, (bf16)v.y, (bf16)v.z, (bf16)v.w };
        *(bf16x4*)&As[m * LDT + k4] = pk;
      }
      const int kp0 = k0 >> 3;
#pragma unroll
      for (int w = 0; w < 2; ++w) {
        const int kpl = kpl0 + w * 2;
        const unsigned int word = (unsigned int)qweight[(kp0 + kpl) * NDIM + gn];
        bf16x8 pk;
#pragma unroll
        for (int j = 0; j < 8; ++j) {
          const float q = (float)((word >> (4 * j)) & 0xF);
          pk[j] = (bf16)(q * sc - zs);
        }
        const int sw = kpl ^ ((nb >> 3) & 3);
        *(bf16x8*)&Bs[nb * LDT + sw * 8] = pk;
      }
      __syncthreads();
      bf16x8 af[4], bfr[4];
#pragma unroll
      for (int i = 0; i < 4; ++i)
        af[i] = *(bf16x8*)&As[(wm + i * 16 + l16) * LDT + quad * 8];
#pragma unroll
      for (int j = 0; j < 4; ++j) {
        const int nr = wn + j * 16 + l16;
        const int sw = quad ^ ((nr >> 3) & 3);
        bfr[j] = *(bf16x8*)&Bs[nr * LDT + sw * 8];
      }
#pragma unroll
      for (int i = 0; i < 4; ++i)
#pragma unroll
        for (int j = 0; j < 4; ++j)
          acc[i][j] = __builtin_amdgcn_mfma_f32_16x16x32_bf16(af[i], bfr[j], acc[i][j], 0, 0, 0);
      __syncthreads();
    }
  }
#pragma unroll
  for (int i = 0; i < 4; ++i) {
#pragma unroll
    for (int j = 0; j < 4; ++j) {
      const int r0 = row0 + wm + i * 16 + quad * 4;
      const int c  = col0 + wn + j * 16 + l16;
#pragma unroll
      for (int r = 0; r < 4; ++r)
        out[(r0 + r) * NDIM + c] = acc[i][j][r];
    }
  }
}

extern "C" void kernel_launch(void* const* d_in, const int* in_sizes, int n_in,
                              void* d_out, int out_size, void* d_ws, size_t ws_size,
                              hipStream_t stream) {
  const float* x       = (const float*)d_in[0];
  const int*   qweight = (const int*)d_in[1];
  const int*   qzeros  = (const int*)d_in[2];
  const float* scales  = (const float*)d_in[3];
  float*       out     = (float*)d_out;

  const int M = in_sizes[0] / KDIM;          // 8192

  const size_t xb_bytes = (size_t)M * KDIM * sizeof(bf16);      // 64 MiB
  const size_t wt_bytes = (size_t)NDIM * KDIM * sizeof(bf16);   // 86 MiB

  if (d_ws && ws_size >= xb_bytes + wt_bytes && (M % BM) == 0 &&
      ((M * KDIM) % (8 * 256)) == 0) {
    bf16* xb = (bf16*)d_ws;
    bf16* wt = (bf16*)((char*)d_ws + xb_bytes);
    cvt_x<<<(M * KDIM) / (8 * 256), 256, 0, stream>>>(x, xb);
    dequant_wt<<<dim3(NDIM / 256, KDIM / GROUP), 256, 0, stream>>>(qweight, qzeros, scales, wt);
    gemm_bf16<<<dim3(NDIM / BN, M / BM), 256, 0, stream>>>(xb, wt, out);
  } else {
    gptq_gemm<<<dim3(NDIM / BN, M / BM), 256, 0, stream>>>(x, qweight, qzeros, scales, out);
  }
}